// Round 1
// baseline (301.364 us; speedup 1.0000x reference)
//
#include <hip/hip_runtime.h>

// Problem constants
#define V 32
#define CH 128
#define SP 4096   // 64*64

// ---------------------------------------------------------------------------
// conv_lo: low-res partial 1x1 conv.  out[v,o,s] = sum_c W[o,ko+c]*x[v,c,s]
// (optionally two phases accumulating x3 and x4).  K=128 per phase.
// grid: (spatial/128, 32), block 256.  Tile: 128 o x 128 s, 8x8 per thread.
// ---------------------------------------------------------------------------
__global__ __launch_bounds__(256) void conv_lo(
    const float* __restrict__ xa, const float* __restrict__ xb,
    const float* __restrict__ Wmat, int spatial, int koA, int koB, int nph,
    float* __restrict__ outbuf)
{
    __shared__ float Xl[32][128];
    __shared__ float Wl[32][132];   // [k][o], padded to break bank conflicts
    const int v  = blockIdx.y;
    const int sc = blockIdx.x;
    const int tid = threadIdx.x;
    const int tj = tid & 15;        // s-group: s = tj*8..tj*8+7
    const int ti = tid >> 4;        // o-group: o = ti*8..ti*8+7

    float acc[8][8];
#pragma unroll
    for (int i = 0; i < 8; ++i)
#pragma unroll
        for (int j = 0; j < 8; ++j) acc[i][j] = 0.f;

#pragma unroll 1
    for (int ph = 0; ph < nph; ++ph) {
        const float* xp = ph ? xb : xa;
        const int ko = ph ? koB : koA;
#pragma unroll 1
        for (int k0 = 0; k0 < 128; k0 += 32) {
            // stage X tile [32 k][128 s] (coalesced float4)
#pragma unroll
            for (int p = 0; p < 4; ++p) {
                int f4 = tid + p * 256;
                int kk = f4 >> 5, sg = f4 & 31;
                float4 val = *(const float4*)&xp[(size_t)(v * CH + k0 + kk) * spatial + sc * 128 + sg * 4];
                *(float4*)&Xl[kk][sg * 4] = val;
            }
            // stage W tile transposed [32 k][128 o]
#pragma unroll
            for (int p = 0; p < 4; ++p) {
                int f4 = tid + p * 256;
                int o = f4 >> 3, cg = (f4 & 7) * 4;
                float4 wv = *(const float4*)&Wmat[(size_t)o * 512 + ko + k0 + cg];
                Wl[cg + 0][o] = wv.x; Wl[cg + 1][o] = wv.y;
                Wl[cg + 2][o] = wv.z; Wl[cg + 3][o] = wv.w;
            }
            __syncthreads();
#pragma unroll
            for (int kk = 0; kk < 32; ++kk) {
                float4 w0 = *(const float4*)&Wl[kk][ti * 8];
                float4 w1 = *(const float4*)&Wl[kk][ti * 8 + 4];
                float4 x0 = *(const float4*)&Xl[kk][tj * 8];
                float4 x1v = *(const float4*)&Xl[kk][tj * 8 + 4];
                float wr[8] = {w0.x, w0.y, w0.z, w0.w, w1.x, w1.y, w1.z, w1.w};
                float xr[8] = {x0.x, x0.y, x0.z, x0.w, x1v.x, x1v.y, x1v.z, x1v.w};
#pragma unroll
                for (int i = 0; i < 8; ++i)
#pragma unroll
                    for (int j = 0; j < 8; ++j)
                        acc[i][j] = fmaf(wr[i], xr[j], acc[i][j]);
            }
            __syncthreads();
        }
    }
#pragma unroll
    for (int i = 0; i < 8; ++i) {
        int o = ti * 8 + i;
        size_t base = (size_t)(v * CH + o) * spatial + sc * 128 + tj * 8;
        float4 a0 = {acc[i][0], acc[i][1], acc[i][2], acc[i][3]};
        float4 a1 = {acc[i][4], acc[i][5], acc[i][6], acc[i][7]};
        *(float4*)&outbuf[base] = a0;
        *(float4*)&outbuf[base + 4] = a1;
    }
}

// ---------------------------------------------------------------------------
// conv_full: full-res x1 part + upsampled conv2/conv34 + bias -> x_sm (d_out),
// plus gap[v,o] = sum_s x_sm (atomic partial sums).
// grid: (32 s-chunks of 128, 32 v), block 256.
// ---------------------------------------------------------------------------
__global__ __launch_bounds__(256) void conv_full(
    const float* __restrict__ x1, const float* __restrict__ Wmat,
    const float* __restrict__ bias, const float* __restrict__ conv2,
    const float* __restrict__ conv34, float* __restrict__ xsm,
    float* __restrict__ gap)
{
    __shared__ float Xl[32][128];
    __shared__ float Wl[32][132];
    const int v  = blockIdx.y;
    const int sc = blockIdx.x;
    const int tid = threadIdx.x;
    const int tj = tid & 15;
    const int ti = tid >> 4;

    float acc[8][8];
#pragma unroll
    for (int i = 0; i < 8; ++i)
#pragma unroll
        for (int j = 0; j < 8; ++j) acc[i][j] = 0.f;

#pragma unroll 1
    for (int k0 = 0; k0 < 128; k0 += 32) {
#pragma unroll
        for (int p = 0; p < 4; ++p) {
            int f4 = tid + p * 256;
            int kk = f4 >> 5, sg = f4 & 31;
            float4 val = *(const float4*)&x1[(size_t)(v * CH + k0 + kk) * SP + sc * 128 + sg * 4];
            *(float4*)&Xl[kk][sg * 4] = val;
        }
#pragma unroll
        for (int p = 0; p < 4; ++p) {
            int f4 = tid + p * 256;
            int o = f4 >> 3, cg = (f4 & 7) * 4;
            float4 wv = *(const float4*)&Wmat[(size_t)o * 512 + k0 + cg];
            Wl[cg + 0][o] = wv.x; Wl[cg + 1][o] = wv.y;
            Wl[cg + 2][o] = wv.z; Wl[cg + 3][o] = wv.w;
        }
        __syncthreads();
#pragma unroll
        for (int kk = 0; kk < 32; ++kk) {
            float4 w0 = *(const float4*)&Wl[kk][ti * 8];
            float4 w1 = *(const float4*)&Wl[kk][ti * 8 + 4];
            float4 x0 = *(const float4*)&Xl[kk][tj * 8];
            float4 x1v = *(const float4*)&Xl[kk][tj * 8 + 4];
            float wr[8] = {w0.x, w0.y, w0.z, w0.w, w1.x, w1.y, w1.z, w1.w};
            float xr[8] = {x0.x, x0.y, x0.z, x0.w, x1v.x, x1v.y, x1v.z, x1v.w};
#pragma unroll
            for (int i = 0; i < 8; ++i)
#pragma unroll
                for (int j = 0; j < 8; ++j)
                    acc[i][j] = fmaf(wr[i], xr[j], acc[i][j]);
        }
        __syncthreads();
    }

    // epilogue: s = sc*128 + tj*8 + j ; h = s/64, w = s%64
    const int h  = sc * 2 + (tj >> 3);
    const int w0 = (tj * 8) & 63;
    float gsum[8];
#pragma unroll
    for (int i = 0; i < 8; ++i) {
        int o = ti * 8 + i;
        float b = bias[o];
        float4 c2 = *(const float4*)&conv2[(size_t)(v * CH + o) * 1024 + (h >> 1) * 32 + (w0 >> 1)];
        float2 c34 = *(const float2*)&conv34[(size_t)(v * CH + o) * 256 + (h >> 2) * 16 + (w0 >> 2)];
        float c2a[4] = {c2.x, c2.y, c2.z, c2.w};
        float c34a[2] = {c34.x, c34.y};
        float vals[8]; float gs = 0.f;
#pragma unroll
        for (int j = 0; j < 8; ++j) {
            float val = acc[i][j] + b + c2a[j >> 1] + c34a[j >> 2];
            vals[j] = val; gs += val;
        }
        gsum[i] = gs;
        size_t base = (size_t)(v * CH + o) * SP + sc * 128 + tj * 8;
        float4 a0 = {vals[0], vals[1], vals[2], vals[3]};
        float4 a1 = {vals[4], vals[5], vals[6], vals[7]};
        *(float4*)&xsm[base] = a0;
        *(float4*)&xsm[base + 4] = a1;
    }
    // block-level gap reduction (reuse Wl as scratch; last barrier above covers it)
    float* gpart = &Wl[0][0];   // need 128*16 floats = 8 KB, fits
#pragma unroll
    for (int i = 0; i < 8; ++i) gpart[(ti * 8 + i) * 16 + tj] = gsum[i];
    __syncthreads();
    if (tid < 128) {
        float s = 0.f;
#pragma unroll
        for (int t = 0; t < 16; ++t) s += gpart[tid * 16 + t];
        atomicAdd(&gap[v * CH + tid], s);
    }
}

// ---------------------------------------------------------------------------
// build_G: c_q -> att_C -> softmax*weight -> G = (C_mat+I)(I + gamma*M),
// stored transposed Gt[k][i] (i contiguous).  grid 128 blocks x 128 threads.
// gap holds SUMS over s; divide by 4096 for means.
// ---------------------------------------------------------------------------
__global__ __launch_bounds__(128) void build_G(
    const float* __restrict__ gap, const float* __restrict__ gammap,
    const float* __restrict__ weight, float* __restrict__ Gt)
{
    __shared__ float cq[32][128];
    __shared__ float red[128];
    const int i = blockIdx.x, j = threadIdx.x;
    const float g = gammap[0];

    float gb = 0.f;
    for (int v = 0; v < 32; ++v) gb += gap[v * CH + j];
    gb = gb * (1.f / 32.f) * (1.f / 4096.f) * g;
    for (int v = 0; v < 32; ++v) cq[v][j] = gap[v * CH + j] * (1.f / 4096.f) + gb;
    __syncthreads();

    float a = 0.f;
    for (int v = 0; v < 32; ++v) a += cq[v][i] * cq[v][j];

    red[j] = a; __syncthreads();
    float m = -1e30f;
    for (int t = 0; t < 128; ++t) m = fmaxf(m, red[t]);
    __syncthreads();
    float e = __expf(a - m);
    red[j] = e; __syncthreads();
    float ssum = 0.f;
    for (int t = 0; t < 128; ++t) ssum += red[t];
    float cm = e / ssum * weight[j] + ((i == j) ? 1.f : 0.f);   // (C_mat + I)[i][j]
    __syncthreads();
    red[j] = cm; __syncthreads();
    float rs = 0.f;
    for (int t = (j & 3); t < 128; t += 4) rs += red[t];        // sum over t%4 == j%4
    Gt[j * CH + i] = cm + g * (1.f / 32.f) * rs;
}

// ---------------------------------------------------------------------------
// apply_G: out[v, g*32+r, s] = sum_j G[v*4+g, j] * x_sm[j/4, (j%4)*32+r, s].
// IN-PLACE on xsm (= d_out): block read-set == write-set; full X tile staged
// to LDS before any store.  grid: (64 s-chunks of 64, 32 r), block 256.
// ---------------------------------------------------------------------------
__global__ __launch_bounds__(256) void apply_G(
    float* __restrict__ xsm, const float* __restrict__ Gt)
{
    __shared__ float Xl[128][64];
    __shared__ float Gl[32][132];
    const int r  = blockIdx.y;
    const int sc = blockIdx.x;
    const int tid = threadIdx.x;
    const int tj = tid & 15;   // s = tj*4..tj*4+3
    const int ti = tid >> 4;   // i = ti*8..ti*8+7

    // stage all 128 K-rows first (in-place safety)
#pragma unroll
    for (int p = 0; p < 8; ++p) {
        int f4 = tid + p * 256;
        int j = f4 >> 4, sg = f4 & 15;
        int u = j >> 2, q = j & 3;
        float4 val = *(const float4*)&xsm[(size_t)(u * CH + q * 32 + r) * SP + sc * 64 + sg * 4];
        *(float4*)&Xl[j][sg * 4] = val;
    }
    __syncthreads();

    float acc[8][4];
#pragma unroll
    for (int i = 0; i < 8; ++i)
#pragma unroll
        for (int j = 0; j < 4; ++j) acc[i][j] = 0.f;

#pragma unroll 1
    for (int k0 = 0; k0 < 128; k0 += 32) {
#pragma unroll
        for (int p = 0; p < 4; ++p) {
            int f4 = tid + p * 256;
            int kk = f4 >> 5, ig = f4 & 31;
            float4 gv = *(const float4*)&Gt[(size_t)(k0 + kk) * CH + ig * 4];
            *(float4*)&Gl[kk][ig * 4] = gv;
        }
        __syncthreads();
#pragma unroll
        for (int kk = 0; kk < 32; ++kk) {
            float4 g0 = *(const float4*)&Gl[kk][ti * 8];
            float4 g1 = *(const float4*)&Gl[kk][ti * 8 + 4];
            float4 xv = *(const float4*)&Xl[k0 + kk][tj * 4];
            float gr[8] = {g0.x, g0.y, g0.z, g0.w, g1.x, g1.y, g1.z, g1.w};
            float xr[4] = {xv.x, xv.y, xv.z, xv.w};
#pragma unroll
            for (int i = 0; i < 8; ++i)
#pragma unroll
                for (int j = 0; j < 4; ++j)
                    acc[i][j] = fmaf(gr[i], xr[j], acc[i][j]);
        }
        __syncthreads();
    }
#pragma unroll
    for (int i = 0; i < 8; ++i) {
        int idx = ti * 8 + i;
        int vv = idx >> 2, gg = idx & 3;
        float4 a0 = {acc[i][0], acc[i][1], acc[i][2], acc[i][3]};
        *(float4*)&xsm[(size_t)(vv * CH + gg * 32 + r) * SP + sc * 64 + tj * 4] = a0;
    }
}

// ---------------------------------------------------------------------------
extern "C" void kernel_launch(void* const* d_in, const int* in_sizes, int n_in,
                              void* d_out, int out_size, void* d_ws, size_t ws_size,
                              hipStream_t stream)
{
    const float* x1     = (const float*)d_in[0];
    const float* x2     = (const float*)d_in[1];
    const float* x3     = (const float*)d_in[2];
    const float* x4     = (const float*)d_in[3];
    const float* conv_w = (const float*)d_in[4];
    const float* conv_b = (const float*)d_in[5];
    const float* gamma  = (const float*)d_in[6];
    const float* weight = (const float*)d_in[7];
    // d_in[8] = lin_w: mathematically unused (vps softmax of row-constant
    // matrix is exactly uniform 1/32 regardless of lin_w).

    float* out = (float*)d_out;     // doubles as the x_sm buffer (in-place pass 2)
    float* ws  = (float*)d_ws;

    // ws layout (floats): conv2[32*128*1024], conv34[32*128*256], gap[4096], Gt[16384]
    float* conv2  = ws;
    float* conv34 = ws + (size_t)4194304;
    float* gap    = ws + (size_t)5242880;
    float* Gt     = ws + (size_t)5246976;

    hipMemsetAsync(gap, 0, 4096 * sizeof(float), stream);

    // low-res partial convs
    conv_lo<<<dim3(8, 32), 256, 0, stream>>>(x2, x2, conv_w, 1024, 128, 128, 1, conv2);
    conv_lo<<<dim3(2, 32), 256, 0, stream>>>(x3, x4, conv_w, 256, 256, 384, 2, conv34);
    // full-res conv + combine + bias -> x_sm (in d_out), gap sums
    conv_full<<<dim3(32, 32), 256, 0, stream>>>(x1, conv_w, conv_b, conv2, conv34, out, gap);
    // tiny attention math -> G (transposed)
    build_G<<<128, 128, 0, stream>>>(gap, gamma, weight, Gt);
    // channel-attention GEMM, in place on d_out
    apply_G<<<dim3(64, 32), 256, 0, stream>>>(out, Gt);
}

// Round 2
// 214.700 us; speedup vs baseline: 1.4037x; 1.4037x over previous
//
#include <hip/hip_runtime.h>

// Problem constants
#define V 32
#define CH 128
#define SP 4096   // 64*64

typedef __attribute__((ext_vector_type(8))) short bf16x8;
typedef __attribute__((ext_vector_type(4))) float f32x4;

__device__ __forceinline__ unsigned short bf16rne(float x) {
    union { float f; unsigned u; } v; v.f = x;
    unsigned r = v.u + 0x7fff + ((v.u >> 16) & 1);
    return (unsigned short)(r >> 16);
}

// XOR swizzle on the 8-elem k-block index; keeps both staging b32 writes and
// fragment b128 reads <=2-way bank conflicts (free on gfx950, m136).
__device__ __forceinline__ int xswz(int s) { return (s & 7) ^ ((s >> 2) & 7); }

// row pointer into xsm for the "j" (mixing) index at channel-residue r
__device__ __forceinline__ const float* xsm_row(const float* xsm, int j, int r) {
    return xsm + ((size_t)((j >> 2) * CH + (j & 3) * 32 + r)) * SP;
}

// ---------------------------------------------------------------------------
// prep_w: conv_w f32 [128][512] -> 4 bf16 slabs [sigma][o][c'] stride 136
// ---------------------------------------------------------------------------
__global__ __launch_bounds__(256) void prep_w(const float* __restrict__ W,
                                              unsigned short* __restrict__ Wpad)
{
    int row = blockIdx.x;           // 0..511 = sigma*128 + o
    int j = threadIdx.x;
    if (j < 136) {
        int sigma = row >> 7, o = row & 127;
        float v = (j < 128) ? W[o * 512 + sigma * 128 + j] : 0.f;
        Wpad[row * 136 + j] = bf16rne(v);
    }
}

// ---------------------------------------------------------------------------
// conv_lo: MFMA 1x1 conv partial at low res.  out[v,o,s] = sum_c W*x  (nph
// phases).  Tile M=128 o x N=64 s x K=128/phase.  grid (spatial/64, 32 v).
// ---------------------------------------------------------------------------
__global__ __launch_bounds__(256) void conv_lo(
    const float* __restrict__ xa, const float* __restrict__ xb,
    const unsigned short* __restrict__ WA, const unsigned short* __restrict__ WB,
    int spatial, int nph, float* __restrict__ outbuf)
{
    __shared__ __align__(16) unsigned short Wl[128 * 136];
    __shared__ __align__(16) unsigned short Xl[64 * 128];
    const int v = blockIdx.y, sc = blockIdx.x, tid = threadIdx.x;
    const int lane = tid & 63, w = tid >> 6;
    const int l15 = lane & 15, quad = lane >> 4;
    const int o0 = (w >> 1) * 64, s0 = (w & 1) * 32;
    const int sq = tid & 15, cp0 = tid >> 4;

    f32x4 acc[4][2];
#pragma unroll
    for (int it = 0; it < 4; ++it)
#pragma unroll
        for (int st = 0; st < 2; ++st) acc[it][st] = (f32x4){0.f, 0.f, 0.f, 0.f};

#pragma unroll 1
    for (int ph = 0; ph < nph; ++ph) {
        if (ph) __syncthreads();
        const float* xp = ph ? xb : xa;
        const unsigned short* wp = ph ? WB : WA;
        // stage W slab (straight copy, already padded bf16)
        {
            const float4* wsrc = (const float4*)wp;
            float4* wdst = (float4*)Wl;
            for (int idx = tid; idx < 2176; idx += 256) wdst[idx] = wsrc[idx];
        }
        // stage X tile transposed: [128 c][64 s] f32 -> Xl[s][c] bf16 (swizzled)
        const float* xbase = xp + (size_t)v * CH * spatial + sc * 64;
#pragma unroll
        for (int rep = 0; rep < 4; ++rep) {
            int c = (cp0 + rep * 16) * 2;
            const float* r0 = xbase + (size_t)c * spatial + sq * 4;
            float4 va = *(const float4*)r0;
            float4 vb = *(const float4*)(r0 + spatial);
            float a4[4] = {va.x, va.y, va.z, va.w};
            float b4[4] = {vb.x, vb.y, vb.z, vb.w};
#pragma unroll
            for (int i = 0; i < 4; ++i) {
                int s = sq * 4 + i;
                ushort2 pk; pk.x = bf16rne(a4[i]); pk.y = bf16rne(b4[i]);
                *(ushort2*)&Xl[s * 128 + (((c >> 3) ^ xswz(s)) * 8) + (c & 7)] = pk;
            }
        }
        __syncthreads();
#pragma unroll
        for (int ks = 0; ks < 4; ++ks) {
            int kb = ks * 4 + quad;
            bf16x8 af[4], bfr[2];
#pragma unroll
            for (int it = 0; it < 4; ++it)
                af[it] = *(const bf16x8*)&Wl[(o0 + it * 16 + l15) * 136 + ks * 32 + quad * 8];
#pragma unroll
            for (int st = 0; st < 2; ++st) {
                int s = s0 + st * 16 + l15;
                bfr[st] = *(const bf16x8*)&Xl[s * 128 + ((kb ^ xswz(s)) * 8)];
            }
#pragma unroll
            for (int it = 0; it < 4; ++it)
#pragma unroll
                for (int st = 0; st < 2; ++st)
                    acc[it][st] = __builtin_amdgcn_mfma_f32_16x16x32_bf16(
                        af[it], bfr[st], acc[it][st], 0, 0, 0);
        }
    }
#pragma unroll
    for (int it = 0; it < 4; ++it)
#pragma unroll
        for (int reg = 0; reg < 4; ++reg) {
            int o = o0 + it * 16 + quad * 4 + reg;
            float* orow = outbuf + ((size_t)(v * CH + o)) * spatial + sc * 64;
#pragma unroll
            for (int st = 0; st < 2; ++st) {
                int s_l = s0 + st * 16 + l15;
                orow[s_l] = acc[it][st][reg];
            }
        }
}

// ---------------------------------------------------------------------------
// conv_full: x1 MFMA conv (K=128) + upsampled conv2/conv34 + bias -> xsm,
// plus gap[v][o] partial sums.  grid (64 sc, 32 v).
// ---------------------------------------------------------------------------
__global__ __launch_bounds__(256) void conv_full(
    const float* __restrict__ x1, const unsigned short* __restrict__ W0,
    const float* __restrict__ bias, const float* __restrict__ conv2,
    const float* __restrict__ conv34, float* __restrict__ xsm,
    float* __restrict__ gap)
{
    __shared__ __align__(16) unsigned short Wl[128 * 136];
    __shared__ __align__(16) unsigned short Xl[64 * 128];
    __shared__ float gscr[4][64];
    const int v = blockIdx.y, sc = blockIdx.x, tid = threadIdx.x;
    const int lane = tid & 63, w = tid >> 6;
    const int l15 = lane & 15, quad = lane >> 4;
    const int o0 = (w >> 1) * 64, s0 = (w & 1) * 32;
    const int sq = tid & 15, cp0 = tid >> 4;

    f32x4 acc[4][2];
#pragma unroll
    for (int it = 0; it < 4; ++it)
#pragma unroll
        for (int st = 0; st < 2; ++st) acc[it][st] = (f32x4){0.f, 0.f, 0.f, 0.f};

    {
        const float4* wsrc = (const float4*)W0;
        float4* wdst = (float4*)Wl;
        for (int idx = tid; idx < 2176; idx += 256) wdst[idx] = wsrc[idx];
    }
    const float* xbase = x1 + (size_t)v * CH * SP + sc * 64;
#pragma unroll
    for (int rep = 0; rep < 4; ++rep) {
        int c = (cp0 + rep * 16) * 2;
        const float* r0 = xbase + (size_t)c * SP + sq * 4;
        float4 va = *(const float4*)r0;
        float4 vb = *(const float4*)(r0 + SP);
        float a4[4] = {va.x, va.y, va.z, va.w};
        float b4[4] = {vb.x, vb.y, vb.z, vb.w};
#pragma unroll
        for (int i = 0; i < 4; ++i) {
            int s = sq * 4 + i;
            ushort2 pk; pk.x = bf16rne(a4[i]); pk.y = bf16rne(b4[i]);
            *(ushort2*)&Xl[s * 128 + (((c >> 3) ^ xswz(s)) * 8) + (c & 7)] = pk;
        }
    }
    __syncthreads();
#pragma unroll
    for (int ks = 0; ks < 4; ++ks) {
        int kb = ks * 4 + quad;
        bf16x8 af[4], bfr[2];
#pragma unroll
        for (int it = 0; it < 4; ++it)
            af[it] = *(const bf16x8*)&Wl[(o0 + it * 16 + l15) * 136 + ks * 32 + quad * 8];
#pragma unroll
        for (int st = 0; st < 2; ++st) {
            int s = s0 + st * 16 + l15;
            bfr[st] = *(const bf16x8*)&Xl[s * 128 + ((kb ^ xswz(s)) * 8)];
        }
#pragma unroll
        for (int it = 0; it < 4; ++it)
#pragma unroll
            for (int st = 0; st < 2; ++st)
                acc[it][st] = __builtin_amdgcn_mfma_f32_16x16x32_bf16(
                    af[it], bfr[st], acc[it][st], 0, 0, 0);
    }

    // epilogue: + bias + up2(conv2) + up4(conv34); write xsm f32; gap sums
    const float* c2row = conv2 + (size_t)v * CH * 1024 + (sc >> 1) * 32;
    const float* c34row = conv34 + (size_t)v * CH * 256 + (sc >> 2) * 16;
    float gs[16];
#pragma unroll
    for (int it = 0; it < 4; ++it)
#pragma unroll
        for (int reg = 0; reg < 4; ++reg) {
            int o = o0 + it * 16 + quad * 4 + reg;
            float b = bias[o];
            float* orow = xsm + ((size_t)(v * CH + o)) * SP + sc * 64;
            const float* c2p = c2row + (size_t)o * 1024;
            const float* c34p = c34row + (size_t)o * 256;
            float lsum = 0.f;
#pragma unroll
            for (int st = 0; st < 2; ++st) {
                int s_l = s0 + st * 16 + l15;
                float val = acc[it][st][reg] + b + c2p[s_l >> 1] + c34p[s_l >> 2];
                orow[s_l] = val;
                lsum += val;
            }
            gs[it * 4 + reg] = lsum;
        }
#pragma unroll
    for (int m = 1; m < 16; m <<= 1)
#pragma unroll
        for (int k = 0; k < 16; ++k) gs[k] += __shfl_xor(gs[k], m, 64);
    if (l15 == 0) {
#pragma unroll
        for (int it = 0; it < 4; ++it)
#pragma unroll
            for (int reg = 0; reg < 4; ++reg)
                gscr[w][it * 16 + quad * 4 + reg] = gs[it * 4 + reg];
    }
    __syncthreads();
    if (tid < 128) {
        int o = tid, b2 = (o >> 6) * 2;
        atomicAdd(&gap[v * CH + o], gscr[b2][o & 63] + gscr[b2 + 1][o & 63]);
    }
}

// ---------------------------------------------------------------------------
// build_G: gap sums -> c_q -> att_C -> softmax*weight -> Gs = G - I (bf16,
// padded stride 136, [i][j]).  grid 128 (i) x 128 (j).
// ---------------------------------------------------------------------------
__global__ __launch_bounds__(128) void build_G(
    const float* __restrict__ gap, const float* __restrict__ gammap,
    const float* __restrict__ weight, unsigned short* __restrict__ GsPad)
{
    __shared__ float cq[32][128];
    __shared__ float red[128];
    const int i = blockIdx.x, j = threadIdx.x;
    const float g = gammap[0];

    float gb = 0.f;
    for (int v = 0; v < 32; ++v) gb += gap[v * CH + j];
    gb = gb * (1.f / 32.f) * (1.f / 4096.f) * g;
    for (int v = 0; v < 32; ++v) cq[v][j] = gap[v * CH + j] * (1.f / 4096.f) + gb;
    __syncthreads();

    float a = 0.f;
    for (int v = 0; v < 32; ++v) a += cq[v][i] * cq[v][j];

    red[j] = a; __syncthreads();
    float m = -1e30f;
    for (int t = 0; t < 128; ++t) m = fmaxf(m, red[t]);
    __syncthreads();
    float e = __expf(a - m);
    red[j] = e; __syncthreads();
    float ssum = 0.f;
    for (int t = 0; t < 128; ++t) ssum += red[t];
    float cm = e / ssum * weight[j] + ((i == j) ? 1.f : 0.f);   // (C_mat + I)[i][j]
    __syncthreads();
    red[j] = cm; __syncthreads();
    float rs = 0.f;
    for (int t = (j & 3); t < 128; t += 4) rs += red[t];
    float gfull = cm + g * (1.f / 32.f) * rs;
    GsPad[i * 136 + j] = bf16rne(gfull - ((i == j) ? 1.f : 0.f));  // minus identity
}

// ---------------------------------------------------------------------------
// apply_G: out[i=(v,gg)][s] = sum_j Gs[i][j]*Xt[j][s] + xsm[i-row][s] (f32
// residual).  In-place on xsm: per-(r,sc) block read-set == write-set, and
// each lane's residual read address == its own store address.
// grid (64 sc, 32 r).
// ---------------------------------------------------------------------------
__global__ __launch_bounds__(256) void apply_G(
    float* __restrict__ xsm, const unsigned short* __restrict__ GsPad)
{
    __shared__ __align__(16) unsigned short Gl[128 * 136];
    __shared__ __align__(16) unsigned short Xl[64 * 128];
    const int r = blockIdx.y, sc = blockIdx.x, tid = threadIdx.x;
    const int lane = tid & 63, w = tid >> 6;
    const int l15 = lane & 15, quad = lane >> 4;
    const int i0 = (w >> 1) * 64, s0 = (w & 1) * 32;
    const int sq = tid & 15, cp0 = tid >> 4;

    f32x4 acc[4][2];
#pragma unroll
    for (int it = 0; it < 4; ++it)
#pragma unroll
        for (int st = 0; st < 2; ++st) acc[it][st] = (f32x4){0.f, 0.f, 0.f, 0.f};

    {
        const float4* gsrc = (const float4*)GsPad;
        float4* gdst = (float4*)Gl;
        for (int idx = tid; idx < 2176; idx += 256) gdst[idx] = gsrc[idx];
    }
    // stage Xt[j][s] -> Xl[s][j] bf16 (swizzled); j rows gathered from xsm
#pragma unroll
    for (int rep = 0; rep < 4; ++rep) {
        int c = (cp0 + rep * 16) * 2;     // j pair
        const float* r0 = xsm_row(xsm, c, r) + sc * 64 + sq * 4;
        const float* r1 = xsm_row(xsm, c + 1, r) + sc * 64 + sq * 4;
        float4 va = *(const float4*)r0;
        float4 vb = *(const float4*)r1;
        float a4[4] = {va.x, va.y, va.z, va.w};
        float b4[4] = {vb.x, vb.y, vb.z, vb.w};
#pragma unroll
        for (int i = 0; i < 4; ++i) {
            int s = sq * 4 + i;
            ushort2 pk; pk.x = bf16rne(a4[i]); pk.y = bf16rne(b4[i]);
            *(ushort2*)&Xl[s * 128 + (((c >> 3) ^ xswz(s)) * 8) + (c & 7)] = pk;
        }
    }
    __syncthreads();
#pragma unroll
    for (int ks = 0; ks < 4; ++ks) {
        int kb = ks * 4 + quad;
        bf16x8 af[4], bfr[2];
#pragma unroll
        for (int it = 0; it < 4; ++it)
            af[it] = *(const bf16x8*)&Gl[(i0 + it * 16 + l15) * 136 + ks * 32 + quad * 8];
#pragma unroll
        for (int st = 0; st < 2; ++st) {
            int s = s0 + st * 16 + l15;
            bfr[st] = *(const bf16x8*)&Xl[s * 128 + ((kb ^ xswz(s)) * 8)];
        }
#pragma unroll
        for (int it = 0; it < 4; ++it)
#pragma unroll
            for (int st = 0; st < 2; ++st)
                acc[it][st] = __builtin_amdgcn_mfma_f32_16x16x32_bf16(
                    af[it], bfr[st], acc[it][st], 0, 0, 0);
    }
    // epilogue: f32 residual (own write address) + store
#pragma unroll
    for (int it = 0; it < 4; ++it)
#pragma unroll
        for (int reg = 0; reg < 4; ++reg) {
            int i = i0 + it * 16 + quad * 4 + reg;
            float* rowp = (float*)xsm_row(xsm, i, r) + sc * 64;
#pragma unroll
            for (int st = 0; st < 2; ++st) {
                int s_l = s0 + st * 16 + l15;
                rowp[s_l] = rowp[s_l] + acc[it][st][reg];
            }
        }
}

// ---------------------------------------------------------------------------
extern "C" void kernel_launch(void* const* d_in, const int* in_sizes, int n_in,
                              void* d_out, int out_size, void* d_ws, size_t ws_size,
                              hipStream_t stream)
{
    const float* x1     = (const float*)d_in[0];
    const float* x2     = (const float*)d_in[1];
    const float* x3     = (const float*)d_in[2];
    const float* x4     = (const float*)d_in[3];
    const float* conv_w = (const float*)d_in[4];
    const float* conv_b = (const float*)d_in[5];
    const float* gamma  = (const float*)d_in[6];
    const float* weight = (const float*)d_in[7];
    // d_in[8] = lin_w: mathematically unused (row-constant softmax -> uniform)

    float* out = (float*)d_out;     // doubles as x_sm (in-place pass 2)
    float* ws  = (float*)d_ws;

    // ws layout (floats): conv2[4194304], conv34[1048576], gap[4096],
    //                     Wpad bf16 4*128*136 (34816 f), GsPad bf16 128*136 (8704 f)
    float* conv2  = ws;
    float* conv34 = ws + (size_t)4194304;
    float* gap    = ws + (size_t)5242880;
    unsigned short* Wpad  = (unsigned short*)(ws + (size_t)5246976);
    unsigned short* GsPad = (unsigned short*)(ws + (size_t)5281792);

    hipMemsetAsync(gap, 0, 4096 * sizeof(float), stream);

    prep_w<<<512, 256, 0, stream>>>(conv_w, Wpad);
    conv_lo<<<dim3(16, 32), 256, 0, stream>>>(x2, x2, Wpad + 1 * 128 * 136,
                                              Wpad + 1 * 128 * 136, 1024, 1, conv2);
    conv_lo<<<dim3(4, 32), 256, 0, stream>>>(x3, x4, Wpad + 2 * 128 * 136,
                                             Wpad + 3 * 128 * 136, 256, 2, conv34);
    conv_full<<<dim3(64, 32), 256, 0, stream>>>(x1, Wpad, conv_b, conv2, conv34, out, gap);
    build_G<<<128, 128, 0, stream>>>(gap, gamma, weight, GsPad);
    apply_G<<<dim3(64, 32), 256, 0, stream>>>(out, GsPad);
}